// Round 1
// baseline (592803.320 us; speedup 1.0000x reference)
//
#include <hip/hip_runtime.h>
#include <hip/hip_bf16.h>

// B=32, T_ENC=512, steps TD=501, D_ENC=512, N_MEL=160, H=1024, 4H=4096
// aLSTM K = 256(pre)+512(ctx)+1024(ah) = 1792 ; dLSTM K = 512(ctx)+1024(ah)+1024(dh) = 2560
// Persistent-kernel version: entire 501-step recurrence in ONE kernel,
// 256 blocks x 512 threads (1 block/CU, co-resident), 5 device barriers/step.

typedef __hip_bfloat16 bf16;

__device__ __forceinline__ float b2f(bf16 x){ return __bfloat162float(x); }
__device__ __forceinline__ bf16 f2b(float x){ return __float2bfloat16(x); }
__device__ __forceinline__ unsigned short f2bu(float x){
  union { bf16 h; unsigned short u; } cv; cv.h = __float2bfloat16(x); return cv.u;
}
__device__ __forceinline__ float us2f(unsigned short u){
  return __uint_as_float(((unsigned)u) << 16);
}
__device__ __forceinline__ float sig_s(float x){
  if (x > 30.f) return 1.f; if (x < -30.f) return 0.f;
  return 1.f/(1.f+__expf(-x)); }
__device__ __forceinline__ float tanh_s(float x){
  if (x > 15.f) return 1.f; if (x < -15.f) return -1.f;
  float e=__expf(2.f*x); return 1.f-2.f/(e+1.f); }

// ---------------- workspace layout (fp32 elements unless noted) ----------------
constexpr size_t S_MKT   = 32ull*128*512;            // 2,097,152
constexpr size_t OFF_MKT = 0;
constexpr size_t OFF_AC  = OFF_MKT + S_MKT;
constexpr size_t OFF_DC  = OFF_AC + 32*1024;
constexpr size_t OFF_AW  = OFF_DC + 32*1024;
constexpr size_t OFF_AWT = OFF_AW + 32*512;
constexpr size_t OFF_BAR = OFF_AWT + 32*512;         // 2 uints + pad (zeroed each run)
constexpr size_t OFF_XA  = OFF_BAR + 256;            // xcatA [32][1792] = [pre|ctx|ah]
constexpr size_t ZERO_LEN = OFF_XA - OFF_AC;         // 98,560
constexpr size_t OFF_XD  = OFF_XA + 32*1792;         // xcatD [32][2560] = [ctx|ah|dh]
constexpr size_t OFF_GP  = OFF_XD + 32*2560;         // 8 chunks x 32 x 4096
constexpr size_t OFF_LOC = OFF_GP + 8ull*32*4096;    // loc [32][128][512]
constexpr size_t OFF_BIASA = OFF_LOC + 32ull*128*512;
constexpr size_t OFF_BIASD = OFF_BIASA + 4096;
constexpr size_t OFF_WFOLD = OFF_BIASD + 4096;       // 128 x 62
constexpr size_t OFF_QBIAS = OFF_WFOLD + 7936;       // 128 (bq + bl + wl@cb)
constexpr size_t OFF_WQT   = OFF_QBIAS + 128;        // wqT [1024][128]
constexpr size_t OFF_F32_END = OFF_WQT + 1024*128;

constexpr size_t OFF_PRE2B_BYTES = ((OFF_F32_END*4 + 255)/256)*256;
constexpr size_t S_PRE2B = 501ull*32*256;                       // bf16
constexpr size_t OFF_WAT_BYTES = ((OFF_PRE2B_BYTES + S_PRE2B*2 + 255)/256)*256;
constexpr size_t S_WAT = 1792ull*4096;                          // bf16 (k-packed-by-4)
constexpr size_t OFF_WDT_BYTES = OFF_WAT_BYTES + S_WAT*2;
constexpr size_t S_WDT = 2560ull*4096;                          // bf16 (k-packed-by-4)
constexpr size_t WS_NEEDED = OFF_WDT_BYTES + S_WDT*2;           // ~66.4 MB

// output offsets (fp32 elements in d_out)
constexpr size_t OUT_MEL  = 0;
constexpr size_t OUT_GATE = 501ull*32*160;
constexpr size_t OUT_ATTN = OUT_GATE + 501ull*32;

// ---------------- prep kernels ----------------
__global__ void k_zero(float* __restrict__ p, int n){
  int i = blockIdx.x*256 + threadIdx.x;
  if (i < n) p[i] = 0.f;
}

__global__ void k_bias(const float* __restrict__ b1, const float* __restrict__ b2,
                       float* __restrict__ out){
  int i = blockIdx.x*256 + threadIdx.x;
  if (i < 4096) out[i] = b1[i] + b2[i];
}

// fold wl (128x32) into conv weights (32x2x31) -> wfold[128][62]; qbias = bq + bl + wl@cb
__global__ void k_fold(const float* __restrict__ cw, const float* __restrict__ cb,
                       const float* __restrict__ wl, const float* __restrict__ bl,
                       const float* __restrict__ bq,
                       float* __restrict__ wfold, float* __restrict__ qbias){
  int c = threadIdx.x;  // 128 threads, 1 block
  for (int kk = 0; kk < 62; ++kk){
    float a = 0.f;
    for (int o = 0; o < 32; ++o) a += wl[c*32 + o]*cw[o*62 + kk];
    wfold[c*62 + kk] = a;
  }
  float q = bq[c] + bl[c];
  for (int o = 0; o < 32; ++o) q += wl[c*32 + o]*cb[o];
  qbias[c] = q;
}

// wqT[k][c] = wq[c][k]  (128 x 1024 -> 1024 x 128)
__global__ __launch_bounds__(256) void k_wqT(const float* __restrict__ wq,
                                             float* __restrict__ wqT){
  int idx = blockIdx.x*256 + threadIdx.x;   // 131072
  int k = idx >> 7, c = idx & 127;
  wqT[idx] = wq[(size_t)c*1024 + k];
}

// W^T, bf16, k-packed-by-4: dst[((k>>2)*4096 + j)*4 + (k&3)] = bf16(src[j][k-koff])
__global__ __launch_bounds__(256) void k_trans(const float* __restrict__ src, int C,
                                               unsigned short* __restrict__ dst, int koff){
  __shared__ unsigned short tile[64][65];
  int r0 = blockIdx.x*64, c0 = blockIdx.y*64;
  int tx = threadIdx.x & 63, ty = threadIdx.x >> 6;
  for (int rr = ty; rr < 64; rr += 4)
    tile[rr][tx] = f2bu(src[(size_t)(r0+rr)*C + c0 + tx]);
  __syncthreads();
  for (int rr = ty; rr < 64; rr += 4){
    int k = koff + c0 + rr;
    dst[((size_t)(k >> 2)*4096 + (r0 + tx))*4 + (k & 3)] = tile[tx][rr];
  }
}

// prenet -> pre2b[tt][b][j] (bf16)
__global__ __launch_bounds__(256) void k_prenet(const float* __restrict__ mels,
    const float* __restrict__ w1, const float* __restrict__ b1,
    const float* __restrict__ w2, const float* __restrict__ b2,
    bf16* __restrict__ pre2){
  __shared__ float mel[160];
  __shared__ float x1[256];
  int b = blockIdx.x, tid = threadIdx.x;
  for (int ti = 0; ti < 8; ++ti){
    int tt = blockIdx.y*8 + ti;
    if (tt >= 501) break;
    if (tid < 160) mel[tid] = (tt == 0) ? 0.f : mels[((size_t)b*500 + (tt-1))*160 + tid];
    __syncthreads();
    float a = b1[tid];
    for (int k = 0; k < 160; ++k) a += mel[k]*w1[tid*160 + k];
    x1[tid] = fmaxf(a, 0.f);
    __syncthreads();
    float a2 = b2[tid];
    for (int k = 0; k < 256; ++k) a2 += x1[k]*w2[tid*256 + k];
    pre2[((size_t)tt*32 + b)*256 + tid] = f2b(fmaxf(a2, 0.f));
    __syncthreads();
  }
}

// mkT[b][c][t] = dot(enc[b][t][:], wk[c][:]) + bk[c]   (fp32)
__global__ __launch_bounds__(128) void k_memkeys(const float* __restrict__ enc,
    const float* __restrict__ wk, const float* __restrict__ bk, float* __restrict__ mkT){
  __shared__ float er[512];
  int b = blockIdx.x, tid = threadIdx.x;
  for (int i = 0; i < 8; ++i){
    int t = blockIdx.y*8 + i;
    const float* e = enc + ((size_t)b*512 + t)*512;
    for (int k = tid; k < 512; k += 128) er[k] = e[k];
    __syncthreads();
    float a = bk[tid];
    for (int k = 0; k < 512; ++k) a += er[k]*wk[tid*512 + k];
    mkT[((size_t)b*128 + tid)*512 + t] = a;
    __syncthreads();
  }
}

// ---------------- persistent decoder ----------------
struct SMConv { float wf[7936]; float s0[160]; float s1[160]; };  // 33 KB (conv blocks only)
struct SMAttn { float qp[4][128]; float sq[128]; float red[8]; float saw[512]; };

// Sense-reversing grid barrier: agent-scope atomics + device fences (guide G12/G16).
// All 256 blocks are co-resident (1 block/CU: 33KB LDS, <=256 VGPR, 8 waves).
__device__ __forceinline__ void gridbar(unsigned* bar, int nblk){
  __syncthreads();
  if (threadIdx.x == 0){
    __threadfence();  // flush this block's writes device-wide
    unsigned gen = __hip_atomic_load(bar+1, __ATOMIC_RELAXED, __HIP_MEMORY_SCOPE_AGENT);
    if (__hip_atomic_fetch_add(bar, 1u, __ATOMIC_RELAXED, __HIP_MEMORY_SCOPE_AGENT)
        == (unsigned)(nblk-1)){
      __hip_atomic_store(bar, 0u, __ATOMIC_RELAXED, __HIP_MEMORY_SCOPE_AGENT);
      __hip_atomic_fetch_add(bar+1, 1u, __ATOMIC_RELEASE, __HIP_MEMORY_SCOPE_AGENT);
    } else {
      while (__hip_atomic_load(bar+1, __ATOMIC_ACQUIRE, __HIP_MEMORY_SCOPE_AGENT) == gen)
        __builtin_amdgcn_s_sleep(1);
    }
    __threadfence();  // acquire other blocks' writes
  }
  __syncthreads();
}

// skinny-GEMM partial: 32 j-tiles of 128 x (4096/CH... ) chunks; block = 128 j x 4 b-groups(8 b).
// W is bf16 k-packed-by-4: one ushort4 per lane per 4 k.
template<int CH, int KS>
__device__ __forceinline__ void gates_partial(const unsigned short* __restrict__ Wt,
    const float* __restrict__ xcat, float* __restrict__ Gp, int blk, int tid){
  const int cid = blk >> 5, jt = blk & 31;
  const int j = jt*128 + (tid & 127);
  const int bg = tid >> 7;
  const int k0 = cid*CH;
  float acc[8];
  #pragma unroll
  for (int i = 0; i < 8; ++i) acc[i] = 0.f;
  const float* xb = xcat + (size_t)(bg*8)*KS + k0;
  for (int kk = 0; kk < CH; kk += 4){
    const int k = k0 + kk;
    ushort4 wv4 = *reinterpret_cast<const ushort4*>(Wt + ((size_t)(k >> 2)*4096 + j)*4);
    float w0 = us2f(wv4.x), w1 = us2f(wv4.y), w2 = us2f(wv4.z), w3 = us2f(wv4.w);
    #pragma unroll
    for (int bb = 0; bb < 8; ++bb){
      float4 xv = *reinterpret_cast<const float4*>(xb + (size_t)bb*KS + kk);
      acc[bb] = fmaf(xv.x, w0, acc[bb]);
      acc[bb] = fmaf(xv.y, w1, acc[bb]);
      acc[bb] = fmaf(xv.z, w2, acc[bb]);
      acc[bb] = fmaf(xv.w, w3, acc[bb]);
    }
  }
  float* gp = Gp + (size_t)cid*131072 + (size_t)(bg*8)*4096 + j;
  #pragma unroll
  for (int bb = 0; bb < 8; ++bb) gp[(size_t)bb*4096] = acc[bb];
}

// output projection: 32*161 dot-products of length 1536, one wave per output
__device__ __forceinline__ void out_proj(int wid, int lane, int t,
    const float* __restrict__ xcatD, const float* __restrict__ wm,
    const float* __restrict__ bm, const float* __restrict__ wg,
    const float* __restrict__ bg,
    float* __restrict__ melOut, float* __restrict__ gateOut, int stride){
  for (int oidx = wid; oidx < 32*161; oidx += stride){
    int b = oidx / 161, jo = oidx - b*161;
    const float* wrow = (jo < 160) ? (wm + (size_t)jo*1536) : wg;
    const float* xd = xcatD + (size_t)b*2560;
    float a = 0.f;
    for (int k = lane; k < 1536; k += 64){
      float x = (k < 1024) ? xd[1536 + k] : xd[k - 1024];  // h = [dh | ctx]
      a = fmaf(x, wrow[k], a);
    }
    #pragma unroll
    for (int off = 32; off; off >>= 1) a += __shfl_down(a, off, 64);
    if (lane == 0){
      if (jo < 160) melOut[((size_t)t*32 + b)*160 + jo] = a + bm[jo];
      else gateOut[t*32 + b] = a + bg[0];
    }
  }
}

__global__ __launch_bounds__(512) void k_decoder(
    const unsigned short* __restrict__ WaT, const unsigned short* __restrict__ WdT,
    const float* __restrict__ biasA, const float* __restrict__ biasD,
    const bf16* __restrict__ pre2b, const float* __restrict__ mkT,
    const float* __restrict__ enc, const unsigned char* __restrict__ mask,
    const float* __restrict__ wqT, const float* __restrict__ qbias,
    const float* __restrict__ wfold, const float* __restrict__ waf,
    const float* __restrict__ ba, const float* __restrict__ wm,
    const float* __restrict__ bm, const float* __restrict__ wg,
    const float* __restrict__ bg,
    float* __restrict__ xcatA, float* __restrict__ xcatD,
    float* __restrict__ ac, float* __restrict__ dc,
    float* __restrict__ aw, float* __restrict__ awt,
    float* __restrict__ Gp, float* __restrict__ loc,
    unsigned* __restrict__ bar,
    float* __restrict__ melOut, float* __restrict__ gateOut, float* __restrict__ attnOut)
{
  __shared__ __align__(16) char smraw[sizeof(SMConv)];
  const int blk = blockIdx.x, tid = threadIdx.x;
  const int lane = tid & 63, wv = tid >> 6;

  // ---- pre-phase: init xcat buffers; conv blocks stage folded weights once ----
  for (int idx = blk*512 + tid; idx < 32*1792; idx += 131072){
    int b = idx / 1792, i = idx - b*1792;
    xcatA[idx] = (i < 256) ? b2f(pre2b[b*256 + i]) : 0.f;   // pre slot = t=0 row
  }
  for (int idx = blk*512 + tid; idx < 32*2560; idx += 131072) xcatD[idx] = 0.f;
  if (blk >= 128){
    SMConv* smc = (SMConv*)smraw;
    for (int i = tid; i < 7936; i += 512) smc->wf[i] = wfold[i];  // persists all steps
  }
  gridbar(bar, 256);

  for (int t = 0; t < 501; ++t){
    // ---- P1: gatesA partials (blocks 0..127) | location conv (blocks 128..255) ----
    if (blk < 128){
      gates_partial<448, 1792>(WaT, xcatA, Gp, blk, tid);
    } else {
      SMConv* smc = (SMConv*)smraw;
      int cb = blk - 128;
      int b = cb >> 2, tc = cb & 3;
      int tbase = tc*128;
      for (int i = tid; i < 316; i += 512){
        int ch = (i >= 158), p = ch ? i - 158 : i;
        int pos = tbase + p - 15;
        float v = (pos >= 0 && pos < 512) ? (ch ? awt[b*512 + pos] : aw[b*512 + pos]) : 0.f;
        if (ch) smc->s1[p] = v; else smc->s0[p] = v;
      }
      __syncthreads();
      int tt = tid & 127, cgq = tid >> 7;
      float w0[31], w1[31];
      #pragma unroll
      for (int k = 0; k < 31; ++k){ w0[k] = smc->s0[tt + k]; w1[k] = smc->s1[tt + k]; }
      const float* wfr = smc->wf + cgq*32*62;
      float* lr = loc + ((size_t)b*128 + cgq*32)*512 + tbase + tt;
      for (int cq = 0; cq < 32; ++cq){
        float a = 0.f;
        #pragma unroll
        for (int k = 0; k < 31; ++k)
          a = fmaf(wfr[cq*62 + k], w0[k], fmaf(wfr[cq*62 + 31 + k], w1[k], a));
        lr[(size_t)cq*512] = a;
      }
    }
    gridbar(bar, 256);

    // ---- P2: cellA (blocks 0..63) | out(t-1) (blocks 64..95) ----
    if (blk < 64){
      int idx = blk*512 + tid;
      int b = idx >> 10, u = idx & 1023;
      float gi = biasA[u], gf = biasA[1024+u], gg = biasA[2048+u], go = biasA[3072+u];
      #pragma unroll
      for (int ci = 0; ci < 4; ++ci){
        const float* p = Gp + (size_t)ci*131072 + (size_t)b*4096 + u;
        gi += p[0]; gf += p[1024]; gg += p[2048]; go += p[3072];
      }
      float cp = ac[idx];
      float cn = sig_s(gf)*cp + sig_s(gi)*tanh_s(gg);
      float hh = sig_s(go)*tanh_s(cn);
      ac[idx] = cn;
      xcatA[(size_t)b*1792 + 768 + u] = hh;
      xcatD[(size_t)b*2560 + 512 + u] = hh;
    } else if (blk < 96){
      if (t > 0)
        out_proj((blk-64)*8 + wv, lane, t-1, xcatD, wm, bm, wg, bg, melOut, gateOut, 256);
    }
    gridbar(bar, 256);

    // ---- P3: attention (blocks 0..31, one per batch) ----
    if (blk < 32){
      SMAttn* sma = (SMAttn*)smraw;
      int b = blk;
      {  // query = ah @ wq.T (wqT transposed: coalesced over c)
        int c = tid & 127, kq = tid >> 7;
        const float* ahb = xcatA + (size_t)b*1792 + 768 + kq*256;
        const float* wt = wqT + (size_t)(kq*256)*128 + c;
        float p = 0.f;
        for (int k = 0; k < 256; ++k) p = fmaf(ahb[k], wt[(size_t)k*128], p);
        sma->qp[kq][c] = p;
      }
      __syncthreads();
      if (tid < 128)
        sma->sq[tid] = sma->qp[0][tid] + sma->qp[1][tid] + sma->qp[2][tid] + sma->qp[3][tid]
                     + qbias[tid];
      __syncthreads();
      float e;
      {
        const float* mk = mkT + (size_t)b*65536 + tid;
        const float* lc = loc + (size_t)b*65536 + tid;
        float a = 0.f;
        for (int c = 0; c < 128; ++c){
          float s = sma->sq[c] + mk[(size_t)c*512] + lc[(size_t)c*512];
          a = fmaf(tanh_s(s), waf[c], a);
        }
        e = a + ba[0];
        if (mask[b*512 + tid]) e = -1e30f;
      }
      // softmax over t (512 positions, 8 waves)
      float m = e;
      #pragma unroll
      for (int off = 32; off; off >>= 1) m = fmaxf(m, __shfl_down(m, off, 64));
      if (lane == 0) sma->red[wv] = m;
      __syncthreads();
      if (tid == 0){ float mm = sma->red[0];
        for (int i = 1; i < 8; ++i) mm = fmaxf(mm, sma->red[i]); sma->red[0] = mm; }
      __syncthreads();
      float M = sma->red[0];
      __syncthreads();
      float pe = __expf(e - M);
      float s = pe;
      #pragma unroll
      for (int off = 32; off; off >>= 1) s += __shfl_down(s, off, 64);
      if (lane == 0) sma->red[wv] = s;
      __syncthreads();
      if (tid == 0){ float ss = 0.f; for (int i = 0; i < 8; ++i) ss += sma->red[i];
        sma->red[0] = ss; }
      __syncthreads();
      float av = pe / sma->red[0];
      aw[b*512 + tid] = av;
      awt[b*512 + tid] += av;
      attnOut[((size_t)t*32 + b)*512 + tid] = av;
      sma->saw[tid] = av;
      __syncthreads();
      {  // ctx[b][d] = sum_t aw[t]*enc[b][t][d]
        const float* eb = enc + (size_t)b*262144 + tid;
        float a = 0.f;
        for (int tt2 = 0; tt2 < 512; ++tt2) a = fmaf(sma->saw[tt2], eb[(size_t)tt2*512], a);
        xcatA[(size_t)b*1792 + 256 + tid] = a;
        xcatD[(size_t)b*2560 + tid] = a;
      }
    }
    gridbar(bar, 256);

    // ---- P4: gatesD partials (all 256 blocks; 8 chunks of 320 over contiguous xcatD) ----
    gates_partial<320, 2560>(WdT, xcatD, Gp, blk, tid);
    gridbar(bar, 256);

    // ---- P5: cellD (blocks 0..63) | pre2b(t+1) -> xcatA (blocks 64..95) ----
    if (blk < 64){
      int idx = blk*512 + tid;
      int b = idx >> 10, u = idx & 1023;
      float gi = biasD[u], gf = biasD[1024+u], gg = biasD[2048+u], go = biasD[3072+u];
      #pragma unroll
      for (int ci = 0; ci < 8; ++ci){
        const float* p = Gp + (size_t)ci*131072 + (size_t)b*4096 + u;
        gi += p[0]; gf += p[1024]; gg += p[2048]; go += p[3072];
      }
      float cp = dc[idx];
      float cn = sig_s(gf)*cp + sig_s(gi)*tanh_s(gg);
      float hh = sig_s(go)*tanh_s(cn);
      dc[idx] = cn;
      xcatD[(size_t)b*2560 + 1536 + u] = hh;
    } else if (blk < 96){
      if (t < 500){
        int b = blk - 64;
        for (int i = tid; i < 256; i += 512)
          xcatA[(size_t)b*1792 + i] = b2f(pre2b[((size_t)(t+1)*32 + b)*256 + i]);
      }
    }
    gridbar(bar, 256);
  }

  // final output projection for t=500 (all blocks)
  out_proj(blk*8 + wv, lane, 500, xcatD, wm, bm, wg, bg, melOut, gateOut, 2048);
}

// ---------------- launch ----------------
extern "C" void kernel_launch(void* const* d_in, const int* in_sizes, int n_in,
                              void* d_out, int out_size, void* d_ws, size_t ws_size,
                              hipStream_t stream){
  if (ws_size < WS_NEEDED) return;  // diagnostic: absmax==max|ref| => ws too small

  const float* enc    = (const float*)d_in[0];
  const float* mels   = (const float*)d_in[1];
  const unsigned char* mask = (const unsigned char*)d_in[2];
  const float* w_pre1 = (const float*)d_in[3];
  const float* b_pre1 = (const float*)d_in[4];
  const float* w_pre2 = (const float*)d_in[5];
  const float* b_pre2 = (const float*)d_in[6];
  const float* wih_a  = (const float*)d_in[7];
  const float* whh_a  = (const float*)d_in[8];
  const float* bih_a  = (const float*)d_in[9];
  const float* bhh_a  = (const float*)d_in[10];
  const float* wq     = (const float*)d_in[11];
  const float* bq     = (const float*)d_in[12];
  const float* wk     = (const float*)d_in[13];
  const float* bk     = (const float*)d_in[14];
  const float* conv_w = (const float*)d_in[15];
  const float* conv_b = (const float*)d_in[16];
  const float* wl     = (const float*)d_in[17];
  const float* bl     = (const float*)d_in[18];
  const float* wa     = (const float*)d_in[19];
  const float* ba     = (const float*)d_in[20];
  const float* wih_d  = (const float*)d_in[21];
  const float* whh_d  = (const float*)d_in[22];
  const float* bih_d  = (const float*)d_in[23];
  const float* bhh_d  = (const float*)d_in[24];
  const float* wm     = (const float*)d_in[25];
  const float* bm     = (const float*)d_in[26];
  const float* wg     = (const float*)d_in[27];
  const float* bg     = (const float*)d_in[28];

  float* W = (float*)d_ws;
  float* mkT   = W + OFF_MKT;
  float* ac    = W + OFF_AC;
  float* dc    = W + OFF_DC;
  float* aw    = W + OFF_AW;
  float* awt   = W + OFF_AWT;
  unsigned* bar = (unsigned*)(W + OFF_BAR);
  float* xcatA = W + OFF_XA;
  float* xcatD = W + OFF_XD;
  float* Gp    = W + OFF_GP;
  float* loc   = W + OFF_LOC;
  float* biasA = W + OFF_BIASA;
  float* biasD = W + OFF_BIASD;
  float* wfold = W + OFF_WFOLD;
  float* qbias = W + OFF_QBIAS;
  float* wqT   = W + OFF_WQT;
  unsigned short* WaT = (unsigned short*)((char*)d_ws + OFF_WAT_BYTES);
  unsigned short* WdT = (unsigned short*)((char*)d_ws + OFF_WDT_BYTES);
  bf16* pre2b = (bf16*)((char*)d_ws + OFF_PRE2B_BYTES);

  float* out    = (float*)d_out;
  float* melOut = out + OUT_MEL;
  float* gateOut= out + OUT_GATE;
  float* attnOut= out + OUT_ATTN;

  // ---- prep ----
  k_zero<<<(int)((ZERO_LEN + 255)/256), 256, 0, stream>>>(W + OFF_AC, (int)ZERO_LEN);
  k_bias<<<16, 256, 0, stream>>>(bih_a, bhh_a, biasA);
  k_bias<<<16, 256, 0, stream>>>(bih_d, bhh_d, biasD);
  k_fold<<<1, 128, 0, stream>>>(conv_w, conv_b, wl, bl, bq, wfold, qbias);
  k_wqT<<<512, 256, 0, stream>>>(wq, wqT);
  k_trans<<<dim3(64, 12), 256, 0, stream>>>(wih_a, 768,  WaT, 0);
  k_trans<<<dim3(64, 16), 256, 0, stream>>>(whh_a, 1024, WaT, 768);
  k_trans<<<dim3(64, 24), 256, 0, stream>>>(wih_d, 1536, WdT, 0);
  k_trans<<<dim3(64, 16), 256, 0, stream>>>(whh_d, 1024, WdT, 1536);
  k_prenet<<<dim3(32, 63), 256, 0, stream>>>(mels, w_pre1, b_pre1, w_pre2, b_pre2, pre2b);
  k_memkeys<<<dim3(32, 64), 128, 0, stream>>>(enc, wk, bk, mkT);

  // ---- the whole 501-step recurrence: one persistent kernel ----
  k_decoder<<<256, 512, 0, stream>>>(WaT, WdT, biasA, biasD, pre2b, mkT, enc, mask,
                                     wqT, qbias, wfold, wa, ba, wm, bm, wg, bg,
                                     xcatA, xcatD, ac, dc, aw, awt, Gp, loc, bar,
                                     melOut, gateOut, attnOut);
}

// Round 3
// 137854.260 us; speedup vs baseline: 4.3002x; 4.3002x over previous
//
#include <hip/hip_runtime.h>
#include <hip/hip_bf16.h>

// B=32, T_ENC=512, steps TD=501, D_ENC=512, N_MEL=160, H=1024, 4H=4096
// aLSTM K = 256(pre)+512(ctx)+1024(ah) = 1792 ; dLSTM K = 512(ctx)+1024(ah)+1024(dh) = 2560
// Persistent kernel v2b: gate weights resident in LDS (139 KB/block, loaded once),
// fence-free barriers (relaxed bypass atomics + vmcnt drain), all phases full-grid.
// v2 bug fixed: LDS weight slice copy loaded only half the slice (3584/5120 ushort4
// instead of 7168/10240) -> garbage bf16 -> NaN.

typedef __hip_bfloat16 bf16;

__device__ __forceinline__ float b2f(bf16 x){ return __bfloat162float(x); }
__device__ __forceinline__ bf16 f2b(float x){ return __float2bfloat16(x); }
__device__ __forceinline__ unsigned short f2bu(float x){
  union { bf16 h; unsigned short u; } cv; cv.h = __float2bfloat16(x); return cv.u;
}
__device__ __forceinline__ float us2f(unsigned short u){
  return __uint_as_float(((unsigned)u) << 16);
}
__device__ __forceinline__ float sig_s(float x){
  if (x > 30.f) return 1.f; if (x < -30.f) return 0.f;
  return 1.f/(1.f+__expf(-x)); }
__device__ __forceinline__ float tanh_s(float x){
  if (x > 15.f) return 1.f; if (x < -15.f) return -1.f;
  float e=__expf(2.f*x); return 1.f-2.f/(e+1.f); }

// coherent bypass load/store (agent scope, relaxed: no cache invalidates/writebacks)
__device__ __forceinline__ float ld_cv(const float* p){
  return __hip_atomic_load(p, __ATOMIC_RELAXED, __HIP_MEMORY_SCOPE_AGENT);
}
__device__ __forceinline__ void st_cv(float* p, float v){
  __hip_atomic_store(p, v, __ATOMIC_RELAXED, __HIP_MEMORY_SCOPE_AGENT);
}

// ---------------- workspace layout (fp32 elements unless noted) ----------------
constexpr size_t S_MKT   = 32ull*128*512;
constexpr size_t OFF_MKT = 0;
constexpr size_t OFF_AC  = OFF_MKT + S_MKT;
constexpr size_t OFF_DC  = OFF_AC + 32*1024;
constexpr size_t OFF_AW  = OFF_DC + 32*1024;
constexpr size_t OFF_AWT = OFF_AW + 32*512;
constexpr size_t OFF_BARS= OFF_AWT + 32*512;         // 3072 uints (zeroed)
constexpr size_t OFF_XA  = OFF_BARS + 3072;          // xcatA [32][1792] = [pre|ctx|ah]
constexpr size_t ZERO_LEN = OFF_XA - OFF_AC;
constexpr size_t OFF_XD  = OFF_XA + 32*1792;         // xcatD [32][2560] = [ctx|ah|dh]
constexpr size_t OFF_GP  = OFF_XD + 32*2560;         // 8 chunks x 32 x 4096
constexpr size_t OFF_CNV = OFF_GP + 8ull*32*4096;    // cnv [32][32][512]
constexpr size_t OFF_RED = OFF_CNV + 32ull*32*512;   // redG [32][8][2]
constexpr size_t OFF_BIASA = OFF_RED + 512;
constexpr size_t OFF_BIASD = OFF_BIASA + 4096;
constexpr size_t OFF_WQT   = OFF_BIASD + 4096;       // wqT [1024][128]
constexpr size_t OFF_F32_END = OFF_WQT + 1024*128;

constexpr size_t OFF_PRE2B_BYTES = ((OFF_F32_END*4 + 255)/256)*256;
constexpr size_t S_PRE2B = 501ull*32*256;                       // bf16
constexpr size_t OFF_WAT_BYTES = ((OFF_PRE2B_BYTES + S_PRE2B*2 + 255)/256)*256;
constexpr size_t S_WAT = 1792ull*4096;                          // bf16, per-block slices
constexpr size_t OFF_WDT_BYTES = OFF_WAT_BYTES + S_WAT*2;
constexpr size_t S_WDT = 2560ull*4096;
constexpr size_t WS_NEEDED = OFF_WDT_BYTES + S_WDT*2;           // ~60.1 MB

// LDS: Wa slice 57344 B | Wd slice 81920 B | scratch 23552 B
constexpr int LDS_WA = 57344;
constexpr int LDS_WD = 81920;
constexpr int LDS_SCR = 23552;
constexpr int SMEM_TOTAL = LDS_WA + LDS_WD + LDS_SCR;   // 162,816 <= 163,840

// output offsets (fp32 elements in d_out)
constexpr size_t OUT_MEL  = 0;
constexpr size_t OUT_GATE = 501ull*32*160;
constexpr size_t OUT_ATTN = OUT_GATE + 501ull*32;

// ---------------- prep kernels ----------------
__global__ void k_zero(float* __restrict__ p, int n){
  int i = blockIdx.x*256 + threadIdx.x;
  if (i < n) p[i] = 0.f;
}

__global__ void k_bias(const float* __restrict__ b1, const float* __restrict__ b2,
                       float* __restrict__ out){
  int i = blockIdx.x*256 + threadIdx.x;
  if (i < 4096) out[i] = b1[i] + b2[i];
}

// wqT[k][c] = wq[c][k]
__global__ __launch_bounds__(256) void k_wqT(const float* __restrict__ wq,
                                             float* __restrict__ wqT){
  int idx = blockIdx.x*256 + threadIdx.x;
  int k = idx >> 7, c = idx & 127;
  wqT[idx] = wq[(size_t)c*1024 + k];
}

// W^T bf16, laid out as per-block contiguous LDS slices:
// slice = (kc*32 + jt); within: (klocal>>2)*512 + jl*4 + (klocal&3)  (ushorts)
__global__ __launch_bounds__(256) void k_trans(const float* __restrict__ src, int C,
    unsigned short* __restrict__ dst, int koff, int CH, int SLICE){
  __shared__ unsigned short tile[64][65];
  int r0 = blockIdx.x*64, c0 = blockIdx.y*64;
  int tx = threadIdx.x & 63, ty = threadIdx.x >> 6;
  for (int rr = ty; rr < 64; rr += 4)
    tile[rr][tx] = f2bu(src[(size_t)(r0+rr)*C + c0 + tx]);
  __syncthreads();
  for (int rr = ty; rr < 64; rr += 4){
    int k = koff + c0 + rr;
    int kcc = k / CH, kl = k - kcc*CH;
    int j = r0 + tx, jtt = j >> 7, jl = j & 127;
    dst[(size_t)(kcc*32 + jtt)*SLICE + (size_t)(kl >> 2)*512 + jl*4 + (kl & 3)] = tile[tx][rr];
  }
}

// prenet -> pre2b[tt][b][j] (bf16)
__global__ __launch_bounds__(256) void k_prenet(const float* __restrict__ mels,
    const float* __restrict__ w1, const float* __restrict__ b1,
    const float* __restrict__ w2, const float* __restrict__ b2,
    bf16* __restrict__ pre2){
  __shared__ float mel[160];
  __shared__ float x1[256];
  int b = blockIdx.x, tid = threadIdx.x;
  for (int ti = 0; ti < 8; ++ti){
    int tt = blockIdx.y*8 + ti;
    if (tt >= 501) break;
    if (tid < 160) mel[tid] = (tt == 0) ? 0.f : mels[((size_t)b*500 + (tt-1))*160 + tid];
    __syncthreads();
    float a = b1[tid];
    for (int k = 0; k < 160; ++k) a += mel[k]*w1[tid*160 + k];
    x1[tid] = fmaxf(a, 0.f);
    __syncthreads();
    float a2 = b2[tid];
    for (int k = 0; k < 256; ++k) a2 += x1[k]*w2[tid*256 + k];
    pre2[((size_t)tt*32 + b)*256 + tid] = f2b(fmaxf(a2, 0.f));
    __syncthreads();
  }
}

// mkT[b][c][t] = dot(enc[b][t][:], wk[c][:]) + bk[c]
__global__ __launch_bounds__(128) void k_memkeys(const float* __restrict__ enc,
    const float* __restrict__ wk, const float* __restrict__ bk, float* __restrict__ mkT){
  __shared__ float er[512];
  int b = blockIdx.x, tid = threadIdx.x;
  for (int i = 0; i < 8; ++i){
    int t = blockIdx.y*8 + i;
    const float* e = enc + ((size_t)b*512 + t)*512;
    for (int k = tid; k < 512; k += 128) er[k] = e[k];
    __syncthreads();
    float a = bk[tid];
    for (int k = 0; k < 512; ++k) a += er[k]*wk[tid*512 + k];
    mkT[((size_t)b*128 + tid)*512 + t] = a;
    __syncthreads();
  }
}

// ---------------- persistent decoder ----------------
// Barrier: one counter per barrier instance, no reset (no ABA). Spin on RELAXED
// bypass loads (no L2 invalidates). Ordering: every thread drains its vmem
// (stores+atomics acked at coherence point) before block sync, then one arrive.
__device__ __forceinline__ void gridbar(unsigned* cnt){
  asm volatile("s_waitcnt vmcnt(0) lgkmcnt(0)" ::: "memory");
  __syncthreads();
  if (threadIdx.x == 0){
    __hip_atomic_fetch_add(cnt, 1u, __ATOMIC_RELAXED, __HIP_MEMORY_SCOPE_AGENT);
    while (__hip_atomic_load(cnt, __ATOMIC_RELAXED, __HIP_MEMORY_SCOPE_AGENT) < 256u)
      __builtin_amdgcn_s_sleep(16);
  }
  __syncthreads();
}

// skinny-GEMM k-chunk partial from LDS-resident weights.
// block = (jt = blk&31, kc = blk>>5); threads 512 = 128 j x 4 b-groups(8 b).
template<int CH, int KS, int HK>
__device__ __forceinline__ void gates_phase(const unsigned short* __restrict__ smW,
    float* __restrict__ xs, const float* __restrict__ xcat,
    float* __restrict__ Gp, int jt, int kc, int tid){
  const int jl = tid & 127, bg = tid >> 7;
  float acc[8];
  #pragma unroll
  for (int i = 0; i < 8; ++i) acc[i] = 0.f;
  const int k0 = kc*CH;
  for (int h = 0; h < CH/HK; ++h){
    __syncthreads();
    for (int i = tid; i < 32*HK; i += 512){
      int b = i / HK, kk = i - b*HK;
      xs[i] = ld_cv(xcat + (size_t)b*KS + k0 + h*HK + kk);
    }
    __syncthreads();
    for (int kk = 0; kk < HK; kk += 4){
      const ushort4 w4 = *(const ushort4*)(smW + (size_t)((h*HK + kk) >> 2)*512 + jl*4);
      const float w0 = us2f(w4.x), w1 = us2f(w4.y), w2 = us2f(w4.z), w3 = us2f(w4.w);
      #pragma unroll
      for (int bb = 0; bb < 8; ++bb){
        const float4 xv = *(const float4*)&xs[(bg*8 + bb)*HK + kk];
        acc[bb] = fmaf(xv.x, w0, acc[bb]);
        acc[bb] = fmaf(xv.y, w1, acc[bb]);
        acc[bb] = fmaf(xv.z, w2, acc[bb]);
        acc[bb] = fmaf(xv.w, w3, acc[bb]);
      }
    }
  }
  float* gp = Gp + (size_t)kc*131072 + (size_t)(bg*8)*4096 + jt*128 + jl;
  #pragma unroll
  for (int bb = 0; bb < 8; ++bb) st_cv(gp + (size_t)bb*4096, acc[bb]);
}

// output projection: 32*161 dot-products of length 1536, one wave per output
__device__ __forceinline__ void out_proj(int wid, int lane, int t,
    const float* __restrict__ xcatD, const float* __restrict__ wm,
    const float* __restrict__ bm, const float* __restrict__ wg,
    const float* __restrict__ bg,
    float* __restrict__ melOut, float* __restrict__ gateOut, int stride){
  for (int oidx = wid; oidx < 32*161; oidx += stride){
    int b = oidx / 161, jo = oidx - b*161;
    const float* wrow = (jo < 160) ? (wm + (size_t)jo*1536) : wg;
    const float* xd = xcatD + (size_t)b*2560;
    float a = 0.f;
    for (int k = lane; k < 1536; k += 64){
      float x = (k < 1024) ? ld_cv(xd + 1536 + k) : ld_cv(xd + (k - 1024)); // h=[dh|ctx]
      a = fmaf(x, wrow[k], a);
    }
    #pragma unroll
    for (int off = 32; off; off >>= 1) a += __shfl_down(a, off, 64);
    if (lane == 0){
      if (jo < 160) melOut[((size_t)t*32 + b)*160 + jo] = a + bm[jo];
      else gateOut[t*32 + b] = a + bg[0];
    }
  }
}

__global__ __launch_bounds__(512) void k_decoder(
    const unsigned short* __restrict__ WaT, const unsigned short* __restrict__ WdT,
    const float* __restrict__ biasA, const float* __restrict__ biasD,
    const bf16* __restrict__ pre2b, const float* __restrict__ mkT,
    const float* __restrict__ enc, const unsigned char* __restrict__ mask,
    const float* __restrict__ wqT, const float* __restrict__ wl,
    const float* __restrict__ bq, const float* __restrict__ bl,
    const float* __restrict__ wa, const float* __restrict__ ba,
    const float* __restrict__ conv_w, const float* __restrict__ conv_b,
    const float* __restrict__ wm, const float* __restrict__ bm,
    const float* __restrict__ wg, const float* __restrict__ bg,
    float* __restrict__ xcatA, float* __restrict__ xcatD,
    float* __restrict__ ac, float* __restrict__ dc,
    float* __restrict__ aw, float* __restrict__ awt,
    float* __restrict__ Gp, float* __restrict__ cnv,
    float* __restrict__ redG, unsigned* __restrict__ bars,
    float* __restrict__ melOut, float* __restrict__ gateOut, float* __restrict__ attnOut)
{
  extern __shared__ __align__(16) char sm[];
  unsigned short* smWa = (unsigned short*)sm;
  unsigned short* smWd = (unsigned short*)(sm + LDS_WA);
  char* scr = sm + LDS_WA + LDS_WD;
  float* xs   = (float*)scr;               // gates staging [0,20480)
  float* s0   = (float*)scr;               // conv [0,640)
  float* s1   = (float*)(scr + 640);       // conv [640,1280)
  float* wlS  = (float*)scr;               // P3 [0,16384)
  float* ahS  = (float*)(scr + 16384);     // P3 [16384,20480)
  float* qpP  = (float*)(scr + 20480);     // P3 qp then partial [20480,22528)
  float* sqS  = (float*)(scr + 22528);     // [22528,23040)
  float* eT   = (float*)(scr + 23040);     // [23040,23296)  persists P3->P4
  float* sawL = (float*)(scr + 23296);     // [23296,23552)

  const int blk = blockIdx.x, tid = threadIdx.x;
  const int lane = tid & 63, wv = tid >> 6;
  const int jt = blk & 31, kc = blk >> 5;

  // ---- one-time: weight slices -> LDS; init xcat ----
  {
    // Wa slice: 224k x 128j = 28672 ushorts = 7168 ushort4
    const ushort4* sa = (const ushort4*)(WaT + (size_t)(kc*32 + jt)*28672);
    ushort4* da = (ushort4*)smWa;
    for (int i = tid; i < 7168; i += 512) da[i] = sa[i];
    // Wd slice: 320k x 128j = 40960 ushorts = 10240 ushort4
    const ushort4* sd = (const ushort4*)(WdT + (size_t)(kc*32 + jt)*40960);
    ushort4* dd = (ushort4*)smWd;
    for (int i = tid; i < 10240; i += 512) dd[i] = sd[i];
  }
  for (int idx = blk*512 + tid; idx < 32*1792; idx += 131072){
    int b = idx / 1792, i = idx - b*1792;
    st_cv(xcatA + idx, (i < 256) ? b2f(pre2b[b*256 + i]) : 0.f);
  }
  for (int idx = blk*512 + tid; idx < 32*2560; idx += 131072) st_cv(xcatD + idx, 0.f);

  int bi = 0;
  gridbar(bars + bi); ++bi;

  for (int t = 0; t < 501; ++t){
    // ---- P1: gatesA (all 256 blocks, LDS weights) ----
    gates_phase<224, 1792, 112>(smWa, xs, xcatA, Gp, jt, kc, tid);
    gridbar(bars + bi); ++bi;

    // ---- P2: cellA (0..63) | out(t-1) (64..127) | conv (128..255) ----
    if (blk < 64){
      int idx = blk*512 + tid, b = idx >> 10, u = idx & 1023;
      float gi = biasA[u], gf = biasA[1024+u], gg = biasA[2048+u], go = biasA[3072+u];
      #pragma unroll
      for (int ci = 0; ci < 8; ++ci){
        const float* p = Gp + (size_t)ci*131072 + (size_t)b*4096 + u;
        gi += ld_cv(p); gf += ld_cv(p+1024); gg += ld_cv(p+2048); go += ld_cv(p+3072);
      }
      float cp = ac[idx];
      float cn = sig_s(gf)*cp + sig_s(gi)*tanh_s(gg);
      float hh = sig_s(go)*tanh_s(cn);
      ac[idx] = cn;
      st_cv(xcatA + (size_t)b*1792 + 768 + u, hh);
      st_cv(xcatD + (size_t)b*2560 + 512 + u, hh);
    } else if (blk < 128){
      if (t > 0)
        out_proj((blk-64)*8 + wv, lane, t-1, xcatD, wm, bm, wg, bg, melOut, gateOut, 512);
    } else {
      int cb = blk - 128, b = cb >> 2, tc = cb & 3, tbase = tc*128;
      for (int i = tid; i < 316; i += 512){
        int ch = (i >= 158), p2 = ch ? i-158 : i;
        int pos = tbase + p2 - 15;
        float v = (pos >= 0 && pos < 512)
                ? (ch ? ld_cv(awt + b*512 + pos) : ld_cv(aw + b*512 + pos)) : 0.f;
        if (ch) s1[p2] = v; else s0[p2] = v;
      }
      __syncthreads();
      int tt2 = tid & 127, oh = tid >> 7;  // oh 0..3, 8 o each
      float acc[8];
      #pragma unroll
      for (int o = 0; o < 8; ++o) acc[o] = 0.f;
      for (int k = 0; k < 31; ++k){
        float v0 = s0[tt2+k], v1 = s1[tt2+k];
        #pragma unroll
        for (int o = 0; o < 8; ++o){
          int oo = oh*8 + o;
          acc[o] = fmaf(conv_w[oo*62 + k], v0, fmaf(conv_w[oo*62 + 31 + k], v1, acc[o]));
        }
      }
      int tg = tbase + tt2;
      #pragma unroll
      for (int o = 0; o < 8; ++o){
        int oo = oh*8 + o;
        st_cv(cnv + ((size_t)b*32 + oo)*512 + tg, acc[o] + conv_b[oo]);
      }
    }
    gridbar(bars + bi); ++bi;

    // ---- P3: attention energies (all blocks: b = blk>>3, tt = blk&7) ----
    {
      int b = blk >> 3, tt = blk & 7, t0 = tt*64;
      if (tid < 64){  // zero ctx slots (accumulated by P4 atomics)
        st_cv(xcatA + (size_t)b*1792 + 256 + t0 + tid, 0.f);
        st_cv(xcatD + (size_t)b*2560 + t0 + tid, 0.f);
      }
      for (int i = tid; i < 4096; i += 512) wlS[i] = wl[i];
      for (int i = tid; i < 1024; i += 512) ahS[i] = ld_cv(xcatA + (size_t)b*1792 + 768 + i);
      __syncthreads();
      {  // query partials (redundant per b across its 8 tt-blocks; wqT is L2-hot)
        int c = tid & 127, kq = tid >> 7;
        const float* ap = ahS + kq*256;
        const float* wp = wqT + (size_t)(kq*256)*128 + c;
        float p = 0.f;
        for (int k = 0; k < 256; ++k) p = fmaf(ap[k], wp[(size_t)k*128], p);
        qpP[kq*128 + c] = p;
      }
      __syncthreads();
      if (tid < 128)
        sqS[tid] = qpP[tid] + qpP[128+tid] + qpP[256+tid] + qpP[384+tid] + bq[tid] + bl[tid];
      __syncthreads();
      int tl = tid & 63, cg = tid >> 6;
      float rv[32];
      {
        const float* cp2 = cnv + (size_t)b*32*512 + t0 + tl;
        #pragma unroll
        for (int o = 0; o < 32; ++o) rv[o] = ld_cv(cp2 + (size_t)o*512);
      }
      float a = 0.f;
      const float* mkb = mkT + (size_t)b*65536 + t0 + tl;
      for (int ci = 0; ci < 16; ++ci){
        int c = cg*16 + ci;
        const float* wr = wlS + c*32;
        float lc = 0.f;
        #pragma unroll
        for (int o = 0; o < 32; ++o) lc = fmaf(wr[o], rv[o], lc);
        float s = sqS[c] + mkb[(size_t)c*512] + lc;
        a = fmaf(tanh_s(s), wa[c], a);
      }
      qpP[cg*64 + tl] = a;   // reuse qp region as partial (sq read is done)
      __syncthreads();
      if (tid < 64){
        float e = ba[0];
        #pragma unroll
        for (int g = 0; g < 8; ++g) e += qpP[g*64 + tid];
        if (mask[b*512 + t0 + tid]) e = -1e30f;
        eT[tid] = e;
        float m = e;
        #pragma unroll
        for (int off = 32; off; off >>= 1) m = fmaxf(m, __shfl_xor(m, off, 64));
        float pe = __expf(e - m), ss = pe;
        #pragma unroll
        for (int off = 32; off; off >>= 1) ss += __shfl_xor(ss, off, 64);
        if (tid == 0){
          st_cv(redG + (size_t)(b*8 + tt)*2, m);
          st_cv(redG + (size_t)(b*8 + tt)*2 + 1, ss);
        }
      }
    }
    gridbar(bars + bi); ++bi;

    // ---- P4: softmax finish + ctx partial (atomic reduce) ----
    {
      int b = blk >> 3, tt = blk & 7, t0 = tt*64;
      if (tid < 64){
        float mi[8], si[8], M = -1e30f, S = 0.f;
        #pragma unroll
        for (int i = 0; i < 8; ++i){
          mi[i] = ld_cv(redG + (size_t)(b*8 + i)*2);
          si[i] = ld_cv(redG + (size_t)(b*8 + i)*2 + 1);
          M = fmaxf(M, mi[i]);
        }
        #pragma unroll
        for (int i = 0; i < 8; ++i) S += si[i]*__expf(mi[i] - M);
        float av = __expf(eT[tid] - M)/S;
        int tg = t0 + tid;
        st_cv(aw + b*512 + tg, av);
        st_cv(awt + b*512 + tg, ld_cv(awt + b*512 + tg) + av);
        attnOut[((size_t)t*32 + b)*512 + tg] = av;
        sawL[tid] = av;
      }
      __syncthreads();
      {
        float accd = 0.f;
        const float* eb = enc + ((size_t)b*512 + t0)*512 + tid;
        for (int tau = 0; tau < 64; ++tau) accd = fmaf(sawL[tau], eb[(size_t)tau*512], accd);
        __hip_atomic_fetch_add(xcatA + (size_t)b*1792 + 256 + tid, accd,
                               __ATOMIC_RELAXED, __HIP_MEMORY_SCOPE_AGENT);
        __hip_atomic_fetch_add(xcatD + (size_t)b*2560 + tid, accd,
                               __ATOMIC_RELAXED, __HIP_MEMORY_SCOPE_AGENT);
      }
    }
    gridbar(bars + bi); ++bi;

    // ---- P5: gatesD (all blocks, LDS weights) ----
    gates_phase<320, 2560, 160>(smWd, xs, xcatD, Gp, jt, kc, tid);
    gridbar(bars + bi); ++bi;

    // ---- P6: cellD (0..63) | pre2b(t+1) -> xcatA (64..95) ----
    if (blk < 64){
      int idx = blk*512 + tid, b = idx >> 10, u = idx & 1023;
      float gi = biasD[u], gf = biasD[1024+u], gg = biasD[2048+u], go = biasD[3072+u];
      #pragma unroll
      for (int ci = 0; ci < 8; ++ci){
        const float* p = Gp + (size_t)ci*131072 + (size_t)b*4096 + u;
        gi += ld_cv(p); gf += ld_cv(p+1024); gg += ld_cv(p+2048); go += ld_cv(p+3072);
      }
      float cp = dc[idx];
      float cn = sig_s(gf)*cp + sig_s(gi)*tanh_s(gg);
      float hh = sig_s(go)*tanh_s(cn);
      dc[idx] = cn;
      st_cv(xcatD + (size_t)b*2560 + 1536 + u, hh);
    } else if (blk < 96){
      if (t < 500){
        int b = blk - 64;
        for (int i = tid; i < 256; i += 512)
          st_cv(xcatA + (size_t)b*1792 + i, b2f(pre2b[((size_t)(t+1)*32 + b)*256 + i]));
      }
    }
    gridbar(bars + bi); ++bi;
  }

  out_proj(blk*8 + wv, lane, 500, xcatD, wm, bm, wg, bg, melOut, gateOut, 2048);
}

// ---------------- launch ----------------
extern "C" void kernel_launch(void* const* d_in, const int* in_sizes, int n_in,
                              void* d_out, int out_size, void* d_ws, size_t ws_size,
                              hipStream_t stream){
  if (ws_size < WS_NEEDED) return;  // diagnostic: absmax==max|ref| => ws too small

  const float* enc    = (const float*)d_in[0];
  const float* mels   = (const float*)d_in[1];
  const unsigned char* mask = (const unsigned char*)d_in[2];
  const float* w_pre1 = (const float*)d_in[3];
  const float* b_pre1 = (const float*)d_in[4];
  const float* w_pre2 = (const float*)d_in[5];
  const float* b_pre2 = (const float*)d_in[6];
  const float* wih_a  = (const float*)d_in[7];
  const float* whh_a  = (const float*)d_in[8];
  const float* bih_a  = (const float*)d_in[9];
  const float* bhh_a  = (const float*)d_in[10];
  const float* wq     = (const float*)d_in[11];
  const float* bq     = (const float*)d_in[12];
  const float* wk     = (const float*)d_in[13];
  const float* bk     = (const float*)d_in[14];
  const float* conv_w = (const float*)d_in[15];
  const float* conv_b = (const float*)d_in[16];
  const float* wl     = (const float*)d_in[17];
  const float* bl     = (const float*)d_in[18];
  const float* wa     = (const float*)d_in[19];
  const float* ba     = (const float*)d_in[20];
  const float* wih_d  = (const float*)d_in[21];
  const float* whh_d  = (const float*)d_in[22];
  const float* bih_d  = (const float*)d_in[23];
  const float* bhh_d  = (const float*)d_in[24];
  const float* wm     = (const float*)d_in[25];
  const float* bm     = (const float*)d_in[26];
  const float* wg     = (const float*)d_in[27];
  const float* bg     = (const float*)d_in[28];

  float* W = (float*)d_ws;
  float* mkT   = W + OFF_MKT;
  float* ac    = W + OFF_AC;
  float* dc    = W + OFF_DC;
  float* aw    = W + OFF_AW;
  float* awt   = W + OFF_AWT;
  unsigned* bars = (unsigned*)(W + OFF_BARS);
  float* xcatA = W + OFF_XA;
  float* xcatD = W + OFF_XD;
  float* Gp    = W + OFF_GP;
  float* cnv   = W + OFF_CNV;
  float* redG  = W + OFF_RED;
  float* biasA = W + OFF_BIASA;
  float* biasD = W + OFF_BIASD;
  float* wqT   = W + OFF_WQT;
  unsigned short* WaT = (unsigned short*)((char*)d_ws + OFF_WAT_BYTES);
  unsigned short* WdT = (unsigned short*)((char*)d_ws + OFF_WDT_BYTES);
  bf16* pre2b = (bf16*)((char*)d_ws + OFF_PRE2B_BYTES);

  float* out    = (float*)d_out;
  float* melOut = out + OUT_MEL;
  float* gateOut= out + OUT_GATE;
  float* attnOut= out + OUT_ATTN;

  static int smem_set = 0;
  if (!smem_set){
    hipFuncSetAttribute((const void*)k_decoder,
                        hipFuncAttributeMaxDynamicSharedMemorySize, SMEM_TOTAL);
    smem_set = 1;
  }

  // ---- prep ----
  k_zero<<<(int)((ZERO_LEN + 255)/256), 256, 0, stream>>>(W + OFF_AC, (int)ZERO_LEN);
  k_bias<<<16, 256, 0, stream>>>(bih_a, bhh_a, biasA);
  k_bias<<<16, 256, 0, stream>>>(bih_d, bhh_d, biasD);
  k_wqT<<<512, 256, 0, stream>>>(wq, wqT);
  k_trans<<<dim3(64, 12), 256, 0, stream>>>(wih_a, 768,  WaT, 0,    224, 28672);
  k_trans<<<dim3(64, 16), 256, 0, stream>>>(whh_a, 1024, WaT, 768,  224, 28672);
  k_trans<<<dim3(64, 24), 256, 0, stream>>>(wih_d, 1536, WdT, 0,    320, 40960);
  k_trans<<<dim3(64, 16), 256, 0, stream>>>(whh_d, 1024, WdT, 1536, 320, 40960);
  k_prenet<<<dim3(32, 63), 256, 0, stream>>>(mels, w_pre1, b_pre1, w_pre2, b_pre2, pre2b);
  k_memkeys<<<dim3(32, 64), 128, 0, stream>>>(enc, wk, bk, mkT);

  // ---- the whole 501-step recurrence: one persistent kernel ----
  k_decoder<<<256, 512, SMEM_TOTAL, stream>>>(WaT, WdT, biasA, biasD, pre2b, mkT, enc, mask,
                                              wqT, wl, bq, bl, wa, ba, conv_w, conv_b,
                                              wm, bm, wg, bg, xcatA, xcatD, ac, dc, aw, awt,
                                              Gp, cnv, redG, bars, melOut, gateOut, attnOut);
}